// Round 7
// baseline (225.654 us; speedup 1.0000x reference)
//
#include <hip/hip_runtime.h>
#include <cstdint>

#define B_ 2
#define S_ 2048
#define D_ 1024
#define H_ 16
#define DH_ 64

typedef short bf16x8 __attribute__((ext_vector_type(8)));
typedef float f32x4 __attribute__((ext_vector_type(4)));

__device__ inline unsigned short f2bf(float f) {
  unsigned int u = __float_as_uint(f);
  u += 0x7fffu + ((u >> 16) & 1u);
  return (unsigned short)(u >> 16);
}

__device__ inline float bf2f(unsigned short h) {
  return __uint_as_float(((unsigned int)h) << 16);
}

// fast 2^x via v_exp_f32
__device__ inline float fexp2(float x) { return __builtin_amdgcn_exp2f(x); }

// XOR-swizzle within a 128B row: spreads the 16B column slots across banks.
__device__ inline int swz(int row, int bytecol) {
  return row * 128 + (bytecol ^ ((row & 7) << 4));
}

#define GLL(gp, lp)                                                            \
  __builtin_amdgcn_global_load_lds(                                            \
      (const __attribute__((address_space(1))) unsigned int*)(gp),             \
      (__attribute__((address_space(3))) unsigned int*)(lp), 16, 0, 0)

// ---------- cast fp32 -> bf16, vectorized x4 ----------
__global__ __launch_bounds__(256) void k_cast(const float* __restrict__ in,
                                              unsigned short* __restrict__ out, int n4) {
  int i = blockIdx.x * 256 + threadIdx.x;
  if (i >= n4) return;
  float4 v = reinterpret_cast<const float4*>(in)[i];
  ushort4 o;
  o.x = f2bf(v.x); o.y = f2bf(v.y); o.z = f2bf(v.z); o.w = f2bf(v.w);
  reinterpret_cast<ushort4*>(out)[i] = o;
}

// ---------- transpose + cast fp32 [R][C] -> bf16 [C][R] ----------
__global__ __launch_bounds__(256) void k_trcast(const float* __restrict__ in,
                                                unsigned short* __restrict__ out,
                                                int R, int C) {
  __shared__ float tile[32][33];
  int ct = blockIdx.x * 32, rt = blockIdx.y * 32;
  int tx = threadIdx.x, ty = threadIdx.y;
#pragma unroll
  for (int i = 0; i < 32; i += 8)
    tile[ty + i][tx] = in[(size_t)(rt + ty + i) * C + ct + tx];
  __syncthreads();
#pragma unroll
  for (int i = 0; i < 32; i += 8)
    out[(size_t)(ct + ty + i) * R + rt + tx] = f2bf(tile[tx][ty + i]);
}

// ---------- bf16 GEMM: C[M][N] = A[M][K] * BT[N][K]^T + bias ----------
// Tile BM x BN, BK=64, 4 waves (2x2), wave tile (BM/2)x(BN/2), 16x16x32 MFMA.
// XCD-aware bijective block swizzle (requires nwg % 8 == 0).
// If VTout != nullptr, columns >= 2048 (the V third of qkv) are written
// transposed into VT[b,h,dh,s] instead of C.
template <int BM, int BN, typename OutT>
__global__ __launch_bounds__(256) void k_gemm(const unsigned short* __restrict__ A,
                                              const unsigned short* __restrict__ BT,
                                              const float* __restrict__ bias,
                                              OutT* __restrict__ C,
                                              unsigned short* __restrict__ VTout,
                                              int M, int N, int K) {
  constexpr int MT = BM / 32, NT = BN / 32;
  __shared__ unsigned short As[BM * 64];
  __shared__ unsigned short Bs[BN * 64];
  const int t = threadIdx.x;
  const int lane = t & 63;
  const int wave = t >> 6;
  const int wm = wave >> 1, wn = wave & 1;
  const int ln15 = lane & 15, lg = lane >> 4;
  // XCD-aware swizzle: 8 XCDs, contiguous chunk per XCD
  const int nwg = gridDim.x * gridDim.y;
  const int flat = blockIdx.y * gridDim.x + blockIdx.x;
  const int cpx = nwg >> 3;
  const int sid = (flat & 7) * cpx + (flat >> 3);
  const int row0 = (sid % gridDim.x) * BM, col0 = (sid / gridDim.x) * BN;
  f32x4 acc[MT][NT];
#pragma unroll
  for (int i = 0; i < MT; ++i)
#pragma unroll
    for (int j = 0; j < NT; ++j)
      acc[i][j] = (f32x4){0.f, 0.f, 0.f, 0.f};

  for (int k0 = 0; k0 < K; k0 += 64) {
    __syncthreads();
#pragma unroll
    for (int i = 0; i < BM / 32; ++i) {
      int chunk = i * 256 + t;          // 16-byte chunks; 8 chunks per 64-col row
      int r = chunk >> 3;
      int cb = (chunk & 7) * 16;
      GLL((const char*)(A + (size_t)(row0 + r) * K + k0) + cb, (char*)As + chunk * 16);
    }
#pragma unroll
    for (int i = 0; i < BN / 32; ++i) {
      int chunk = i * 256 + t;
      int r = chunk >> 3;
      int cb = (chunk & 7) * 16;
      GLL((const char*)(BT + (size_t)(col0 + r) * K + k0) + cb, (char*)Bs + chunk * 16);
    }
    __syncthreads();
#pragma unroll
    for (int ks = 0; ks < 2; ++ks) {
      bf16x8 af[MT], bf[NT];
#pragma unroll
      for (int mt = 0; mt < MT; ++mt)
        af[mt] = *(const bf16x8*)&As[(wm * (BM / 2) + mt * 16 + ln15) * 64 + ks * 32 + lg * 8];
#pragma unroll
      for (int nt = 0; nt < NT; ++nt)
        bf[nt] = *(const bf16x8*)&Bs[(wn * (BN / 2) + nt * 16 + ln15) * 64 + ks * 32 + lg * 8];
#pragma unroll
      for (int mt = 0; mt < MT; ++mt)
#pragma unroll
        for (int nt = 0; nt < NT; ++nt)
          acc[mt][nt] = __builtin_amdgcn_mfma_f32_16x16x32_bf16(af[mt], bf[nt], acc[mt][nt], 0, 0, 0);
    }
  }
  // epilogue: C/D layout col=lane&15, row=(lane>>4)*4+reg  [measured m89]
#pragma unroll
  for (int mt = 0; mt < MT; ++mt) {
#pragma unroll
    for (int nt = 0; nt < NT; ++nt) {
      int col = col0 + wn * (BN / 2) + nt * 16 + ln15;
      float bv = bias[col];
      if (VTout != nullptr && col >= 2048) {
        // write transposed into VT[b*16+h][dh][s]
        int hd = col - 2048;
        int row = row0 + wm * (BM / 2) + mt * 16 + lg * 4;
        int bb = row >> 11, ss = row & 2047;
        ushort4 o;
        o.x = f2bf(acc[mt][nt][0] + bv);
        o.y = f2bf(acc[mt][nt][1] + bv);
        o.z = f2bf(acc[mt][nt][2] + bv);
        o.w = f2bf(acc[mt][nt][3] + bv);
        *(ushort4*)&VTout[(((size_t)(bb * 16 + (hd >> 6)) * 64) + (hd & 63)) * 2048 + ss] = o;
      } else {
#pragma unroll
        for (int r = 0; r < 4; ++r) {
          int row = row0 + wm * (BM / 2) + mt * 16 + lg * 4 + r;
          float v = acc[mt][nt][r] + bv;
          if constexpr (sizeof(OutT) == 2)
            C[(size_t)row * N + col] = f2bf(v);
          else
            C[(size_t)row * N + col] = v;
        }
      }
    }
  }
}

// ---------- flash attention ----------
// 512 blocks (XCD-swizzled) x 256 threads (4 waves). Block covers 128 q-rows
// of one (b,h); each wave owns 32 q-rows (2 q-groups sharing K/V fragments ->
// halves LDS read traffic per q-row vs 16q/wave). KVBLK=64; K,V staged in LDS
// (double-buffered, XOR-swizzled via pre-swizzled global source). Swapped
// QK^T: mfma(K,Q). Softmax in exp2 domain: Q pre-scaled by (1/sqrt(dh))*log2(e).
__global__ __launch_bounds__(256) void k_attn(const unsigned short* __restrict__ qkv,
                                              const unsigned short* __restrict__ VT,
                                              unsigned short* __restrict__ O) {
  __shared__ unsigned short Ks[2][64 * 64];
  __shared__ unsigned short Vs[2][64 * 64];
  __shared__ unsigned short Ps[4][32 * 64];

  const int bid = blockIdx.x;             // 0..511
  const int xcd = bid & 7, idx = bid >> 3;
  const int bh = xcd + (idx >> 4) * 8;    // 16 consecutive bids share one (b,h) on one XCD
  const int qblk = idx & 15;
  const int b = bh >> 4, h = bh & 15;
  const int t = threadIdx.x, wave = t >> 6, lane = t & 63;
  const int ln15 = lane & 15, lg = lane >> 4;
  const unsigned short* Qb = qkv + (size_t)b * S_ * 3072 + h * 64;
  const unsigned short* Kb = Qb + 1024;
  const unsigned short* Vb = VT + (size_t)bh * 64 * 2048;  // [dh][s]
  const int q0 = qblk * 128 + wave * 32;

  // Q fragments, pre-scaled by (1/sqrt(dh)) * log2(e) for exp2-domain softmax
  const float qsc = 0.125f * 1.4426950408889634f;
  bf16x8 qf[2][2];
#pragma unroll
  for (int qg = 0; qg < 2; ++qg)
#pragma unroll
    for (int ks = 0; ks < 2; ++ks) {
      bf16x8 raw = *(const bf16x8*)&Qb[(size_t)(q0 + qg * 16 + ln15) * 3072 + ks * 32 + lg * 8];
#pragma unroll
      for (int j = 0; j < 8; ++j)
        qf[qg][ks][j] = (short)f2bf(bf2f((unsigned short)raw[j]) * qsc);
    }

  // hoisted staging addresses: 256 threads stage 2 chunks each per buffer
  // chunk c = i*256 + t -> row = c>>3 = (t>>3)+32i, col = t&7; swizzled col
  // gcol = (t&7) ^ (row&7); (row+32i)&7 == row&7 so gcol is i-invariant.
  const int srow = t >> 3;
  const int scol = (t & 7) ^ (srow & 7);
  const unsigned short* kPtr0 = Kb + (size_t)srow * 3072 + scol * 8;
  const unsigned short* vPtr0 = Vb + (size_t)srow * 2048 + scol * 8;
  char* ldsK0 = (char*)&Ks[0][0] + t * 16;
  char* ldsV0 = (char*)&Vs[0][0] + t * 16;

  auto stage = [&](int bi, int kv) {
#pragma unroll
    for (int i = 0; i < 2; ++i) {
      GLL(kPtr0 + (size_t)(kv + 32 * i) * 3072, ldsK0 + bi * 8192 + i * 4096);
      GLL(vPtr0 + kv + (size_t)(32 * i) * 2048, ldsV0 + bi * 8192 + i * 4096);
    }
  };

  f32x4 acc[2][4];
#pragma unroll
  for (int qg = 0; qg < 2; ++qg)
#pragma unroll
    for (int dt = 0; dt < 4; ++dt)
      acc[qg][dt] = (f32x4){0.f, 0.f, 0.f, 0.f};
  float m0 = -1e30f, m1 = -1e30f, l0 = 0.f, l1 = 0.f;
  unsigned short* Pw = Ps[wave];

  stage(0, 0);
  __syncthreads();
  int buf = 0;

  for (int kv = 0; kv < S_; kv += 64) {
    if (kv + 64 < S_) stage(buf ^ 1, kv + 64);

    // ---- QK^T (swapped): st[qg][kg], q = qg*16+ln15, key = kg*16+lg*4+r
    // K fragments read ONCE, reused for both q-groups.
    f32x4 st[2][4];
#pragma unroll
    for (int qg = 0; qg < 2; ++qg)
#pragma unroll
      for (int kg = 0; kg < 4; ++kg)
        st[qg][kg] = (f32x4){0.f, 0.f, 0.f, 0.f};
    __builtin_amdgcn_s_setprio(1);
#pragma unroll
    for (int kg = 0; kg < 4; ++kg) {
      int krow = kg * 16 + ln15;
      bf16x8 kf0 = *(const bf16x8*)((const char*)&Ks[buf][0] + swz(krow, lg * 16));
      bf16x8 kf1 = *(const bf16x8*)((const char*)&Ks[buf][0] + swz(krow, 64 + lg * 16));
      st[0][kg] = __builtin_amdgcn_mfma_f32_16x16x32_bf16(kf0, qf[0][0], st[0][kg], 0, 0, 0);
      st[0][kg] = __builtin_amdgcn_mfma_f32_16x16x32_bf16(kf1, qf[0][1], st[0][kg], 0, 0, 0);
      st[1][kg] = __builtin_amdgcn_mfma_f32_16x16x32_bf16(kf0, qf[1][0], st[1][kg], 0, 0, 0);
      st[1][kg] = __builtin_amdgcn_mfma_f32_16x16x32_bf16(kf1, qf[1][1], st[1][kg], 0, 0, 0);
    }
    __builtin_amdgcn_s_setprio(0);

    // ---- row max per q-group (16 own values, reduce over lg via shfl 16/32)
    float tmax[2];
#pragma unroll
    for (int qg = 0; qg < 2; ++qg) {
      float tm = -1e30f;
#pragma unroll
      for (int kg = 0; kg < 4; ++kg)
        tm = fmaxf(tm, fmaxf(fmaxf(st[qg][kg][0], st[qg][kg][1]),
                             fmaxf(st[qg][kg][2], st[qg][kg][3])));
      tm = fmaxf(tm, __shfl_xor(tm, 16));
      tm = fmaxf(tm, __shfl_xor(tm, 32));
      tmax[qg] = tm;
    }

    // ---- defer-max (log2 domain): rescale only when some max grew by >11
    if (__any((tmax[0] > m0 + 11.0f) || (tmax[1] > m1 + 11.0f))) {
      float n0 = fmaxf(m0, tmax[0]), n1 = fmaxf(m1, tmax[1]);
      float r0 = fexp2(m0 - n0), r1 = fexp2(m1 - n1);
      m0 = n0; m1 = n1; l0 *= r0; l1 *= r1;
#pragma unroll
      for (int dt = 0; dt < 4; ++dt)
#pragma unroll
        for (int r = 0; r < 4; ++r) {
          acc[0][dt][r] *= r0;
          acc[1][dt][r] *= r1;
        }
    }

    // ---- P = exp2(st - m), pack to bf16, store to per-wave swizzled LDS tile
    asm volatile("" ::: "memory");
    float ts[2] = {0.f, 0.f};
#pragma unroll
    for (int qg = 0; qg < 2; ++qg) {
      int prow = qg * 16 + ln15;
      float mq = qg ? m1 : m0;
#pragma unroll
      for (int kg = 0; kg < 4; ++kg) {
        float p0 = fexp2(st[qg][kg][0] - mq);
        float p1 = fexp2(st[qg][kg][1] - mq);
        float p2 = fexp2(st[qg][kg][2] - mq);
        float p3 = fexp2(st[qg][kg][3] - mq);
        ts[qg] += (p0 + p1) + (p2 + p3);
        unsigned int w0, w1;
        asm("v_cvt_pk_bf16_f32 %0, %1, %2" : "=v"(w0) : "v"(p0), "v"(p1));
        asm("v_cvt_pk_bf16_f32 %0, %1, %2" : "=v"(w1) : "v"(p2), "v"(p3));
        *(uint2*)((char*)Pw + swz(prow, kg * 32 + lg * 8)) = make_uint2(w0, w1);
      }
    }
    ts[0] += __shfl_xor(ts[0], 16); ts[0] += __shfl_xor(ts[0], 32);
    ts[1] += __shfl_xor(ts[1], 16); ts[1] += __shfl_xor(ts[1], 32);
    l0 += ts[0]; l1 += ts[1];
    asm volatile("" ::: "memory");

    // ---- PV: acc[qg][dt] += V^T-frag x P^T-frag; V fragments reused for both qg
    __builtin_amdgcn_s_setprio(1);
#pragma unroll
    for (int kc = 0; kc < 2; ++kc) {
      bf16x8 pf0 = *(const bf16x8*)((const char*)Pw + swz(ln15, kc * 64 + lg * 16));
      bf16x8 pf1 = *(const bf16x8*)((const char*)Pw + swz(16 + ln15, kc * 64 + lg * 16));
#pragma unroll
      for (int dt = 0; dt < 4; ++dt) {
        bf16x8 vf = *(const bf16x8*)((const char*)&Vs[buf][0] + swz(dt * 16 + ln15, kc * 64 + lg * 16));
        acc[0][dt] = __builtin_amdgcn_mfma_f32_16x16x32_bf16(vf, pf0, acc[0][dt], 0, 0, 0);
        acc[1][dt] = __builtin_amdgcn_mfma_f32_16x16x32_bf16(vf, pf1, acc[1][dt], 0, 0, 0);
      }
    }
    __builtin_amdgcn_s_setprio(0);
    __syncthreads();
    buf ^= 1;
  }

  // ---- epilogue: out = acc / l, layout D[dh][q] -> O[b, q, h*64+dh]
  float inv0 = 1.f / l0, inv1 = 1.f / l1;
#pragma unroll
  for (int qg = 0; qg < 2; ++qg) {
    float inv = qg ? inv1 : inv0;
    size_t qglob = q0 + qg * 16 + ln15;
    size_t base = ((size_t)b * S_ + qglob) * D_ + h * 64 + lg * 4;
#pragma unroll
    for (int dt = 0; dt < 4; ++dt) {
      ushort4 o;
      o.x = f2bf(acc[qg][dt][0] * inv);
      o.y = f2bf(acc[qg][dt][1] * inv);
      o.z = f2bf(acc[qg][dt][2] * inv);
      o.w = f2bf(acc[qg][dt][3] * inv);
      *(ushort4*)&O[base + (size_t)dt * 16] = o;
    }
  }
}

extern "C" void kernel_launch(void* const* d_in, const int* in_sizes, int n_in,
                              void* d_out, int out_size, void* d_ws, size_t ws_size,
                              hipStream_t stream) {
  const float* x     = (const float*)d_in[0];
  const float* w_qkv = (const float*)d_in[1];
  const float* b_qkv = (const float*)d_in[2];
  const float* w_out = (const float*)d_in[3];
  const float* b_out = (const float*)d_in[4];
  float* out = (float*)d_out;

  char* ws = (char*)d_ws;
  const size_t MiB = (size_t)1 << 20;
  unsigned short* xb   = (unsigned short*)(ws + 0 * MiB);   // 8 MiB  [4096][1024] bf16
  unsigned short* wqT  = (unsigned short*)(ws + 8 * MiB);   // 6 MiB  [3072][1024] bf16
  unsigned short* woT  = (unsigned short*)(ws + 14 * MiB);  // 2 MiB  [1024][1024] bf16
  unsigned short* qkvb = (unsigned short*)(ws + 16 * MiB);  // 24 MiB [4096][3072] bf16 (V third unused)
  unsigned short* VTb  = (unsigned short*)(ws + 40 * MiB);  // 8 MiB  [B*H][64][2048] bf16
  unsigned short* Ab   = (unsigned short*)(ws + 48 * MiB);  // 8 MiB  [4096][1024] bf16

  k_cast<<<4096, 256, 0, stream>>>(x, xb, (B_ * S_ * D_) / 4);
  k_trcast<<<dim3(96, 32), dim3(32, 8), 0, stream>>>(w_qkv, wqT, 1024, 3072);
  k_trcast<<<dim3(32, 32), dim3(32, 8), 0, stream>>>(w_out, woT, 1024, 1024);
  k_gemm<128, 128, unsigned short><<<dim3(32, 24), 256, 0, stream>>>(xb, wqT, b_qkv, qkvb, VTb, 4096, 3072, 1024);
  k_attn<<<512, 256, 0, stream>>>(qkvb, VTb, Ab);
  k_gemm<64, 64, float><<<dim3(64, 16), 256, 0, stream>>>(Ab, woT, b_out, out, nullptr, 4096, 1024, 1024);
}

// Round 8
// 217.105 us; speedup vs baseline: 1.0394x; 1.0394x over previous
//
#include <hip/hip_runtime.h>
#include <cstdint>

#define B_ 2
#define S_ 2048
#define D_ 1024
#define H_ 16
#define DH_ 64

typedef short bf16x8 __attribute__((ext_vector_type(8)));
typedef float f32x4 __attribute__((ext_vector_type(4)));

__device__ inline unsigned short f2bf(float f) {
  unsigned int u = __float_as_uint(f);
  u += 0x7fffu + ((u >> 16) & 1u);
  return (unsigned short)(u >> 16);
}

__device__ inline float bf2f(unsigned short h) {
  return __uint_as_float(((unsigned int)h) << 16);
}

// fast 2^x via v_exp_f32
__device__ inline float fexp2(float x) { return __builtin_amdgcn_exp2f(x); }

// XOR-swizzle within a 128B row: spreads the 16B column slots across banks.
__device__ inline int swz(int row, int bytecol) {
  return row * 128 + (bytecol ^ ((row & 7) << 4));
}

#define GLL(gp, lp)                                                            \
  __builtin_amdgcn_global_load_lds(                                            \
      (const __attribute__((address_space(1))) unsigned int*)(gp),             \
      (__attribute__((address_space(3))) unsigned int*)(lp), 16, 0, 0)

// ---------- fused prep: cast x, transpose-cast w_qkv and w_out ----------
// blocks 0..4095: cast x (fp32->bf16, x4)
// blocks 4096..7167: transpose-cast w_qkv [1024][3072] -> wqT [3072][1024]
// blocks 7168..8191: transpose-cast w_out [1024][1024] -> woT [1024][1024]
__global__ __launch_bounds__(256) void k_prep(const float* __restrict__ x,
                                              unsigned short* __restrict__ xb,
                                              const float* __restrict__ w_qkv,
                                              unsigned short* __restrict__ wqT,
                                              const float* __restrict__ w_out,
                                              unsigned short* __restrict__ woT) {
  __shared__ float tile[32][33];
  const int bid = blockIdx.x;
  const int t = threadIdx.x;
  if (bid < 4096) {
    int i = bid * 256 + t;
    float4 v = reinterpret_cast<const float4*>(x)[i];
    ushort4 o;
    o.x = f2bf(v.x); o.y = f2bf(v.y); o.z = f2bf(v.z); o.w = f2bf(v.w);
    reinterpret_cast<ushort4*>(xb)[i] = o;
    return;
  }
  const float* in;
  unsigned short* out;
  int R, C, bx, by;
  if (bid < 7168) {
    int id = bid - 4096;          // grid was (96,32)
    bx = id % 96; by = id / 96;
    in = w_qkv; out = wqT; R = 1024; C = 3072;
  } else {
    int id = bid - 7168;          // grid was (32,32)
    bx = id & 31; by = id >> 5;
    in = w_out; out = woT; R = 1024; C = 1024;
  }
  int ct = bx * 32, rt = by * 32;
  int tx = t & 31, ty = t >> 5;   // 32 x 8
#pragma unroll
  for (int i = 0; i < 32; i += 8)
    tile[ty + i][tx] = in[(size_t)(rt + ty + i) * C + ct + tx];
  __syncthreads();
#pragma unroll
  for (int i = 0; i < 32; i += 8)
    out[(size_t)(ct + ty + i) * R + rt + tx] = f2bf(tile[tx][ty + i]);
}

// ---------- bf16 GEMM: C[M][N] = A[M][K] * BT[N][K]^T + bias ----------
// Tile BM x BN, BK=64, 4 waves (2x2), wave tile (BM/2)x(BN/2), 16x16x32 MFMA.
// XCD-aware bijective block swizzle (requires nwg % 8 == 0).
// If VTout != nullptr, columns >= 2048 (the V third of qkv) are written
// transposed into VT[b,h,dh,s] instead of C.
template <int BM, int BN, typename OutT>
__global__ __launch_bounds__(256) void k_gemm(const unsigned short* __restrict__ A,
                                              const unsigned short* __restrict__ BT,
                                              const float* __restrict__ bias,
                                              OutT* __restrict__ C,
                                              unsigned short* __restrict__ VTout,
                                              int M, int N, int K) {
  constexpr int MT = BM / 32, NT = BN / 32;
  __shared__ unsigned short As[BM * 64];
  __shared__ unsigned short Bs[BN * 64];
  const int t = threadIdx.x;
  const int lane = t & 63;
  const int wave = t >> 6;
  const int wm = wave >> 1, wn = wave & 1;
  const int ln15 = lane & 15, lg = lane >> 4;
  // XCD-aware swizzle: 8 XCDs, contiguous chunk per XCD
  const int nwg = gridDim.x * gridDim.y;
  const int flat = blockIdx.y * gridDim.x + blockIdx.x;
  const int cpx = nwg >> 3;
  const int sid = (flat & 7) * cpx + (flat >> 3);
  const int row0 = (sid % gridDim.x) * BM, col0 = (sid / gridDim.x) * BN;
  f32x4 acc[MT][NT];
#pragma unroll
  for (int i = 0; i < MT; ++i)
#pragma unroll
    for (int j = 0; j < NT; ++j)
      acc[i][j] = (f32x4){0.f, 0.f, 0.f, 0.f};

  for (int k0 = 0; k0 < K; k0 += 64) {
    __syncthreads();
#pragma unroll
    for (int i = 0; i < BM / 32; ++i) {
      int chunk = i * 256 + t;          // 16-byte chunks; 8 chunks per 64-col row
      int r = chunk >> 3;
      int cb = (chunk & 7) * 16;
      GLL((const char*)(A + (size_t)(row0 + r) * K + k0) + cb, (char*)As + chunk * 16);
    }
#pragma unroll
    for (int i = 0; i < BN / 32; ++i) {
      int chunk = i * 256 + t;
      int r = chunk >> 3;
      int cb = (chunk & 7) * 16;
      GLL((const char*)(BT + (size_t)(col0 + r) * K + k0) + cb, (char*)Bs + chunk * 16);
    }
    __syncthreads();
#pragma unroll
    for (int ks = 0; ks < 2; ++ks) {
      bf16x8 af[MT], bf[NT];
#pragma unroll
      for (int mt = 0; mt < MT; ++mt)
        af[mt] = *(const bf16x8*)&As[(wm * (BM / 2) + mt * 16 + ln15) * 64 + ks * 32 + lg * 8];
#pragma unroll
      for (int nt = 0; nt < NT; ++nt)
        bf[nt] = *(const bf16x8*)&Bs[(wn * (BN / 2) + nt * 16 + ln15) * 64 + ks * 32 + lg * 8];
#pragma unroll
      for (int mt = 0; mt < MT; ++mt)
#pragma unroll
        for (int nt = 0; nt < NT; ++nt)
          acc[mt][nt] = __builtin_amdgcn_mfma_f32_16x16x32_bf16(af[mt], bf[nt], acc[mt][nt], 0, 0, 0);
    }
  }
  // epilogue: C/D layout col=lane&15, row=(lane>>4)*4+reg  [measured m89]
#pragma unroll
  for (int mt = 0; mt < MT; ++mt) {
#pragma unroll
    for (int nt = 0; nt < NT; ++nt) {
      int col = col0 + wn * (BN / 2) + nt * 16 + ln15;
      float bv = bias[col];
      if (VTout != nullptr && col >= 2048) {
        // write transposed into VT[b*16+h][dh][s]
        int hd = col - 2048;
        int row = row0 + wm * (BM / 2) + mt * 16 + lg * 4;
        int bb = row >> 11, ss = row & 2047;
        ushort4 o;
        o.x = f2bf(acc[mt][nt][0] + bv);
        o.y = f2bf(acc[mt][nt][1] + bv);
        o.z = f2bf(acc[mt][nt][2] + bv);
        o.w = f2bf(acc[mt][nt][3] + bv);
        *(ushort4*)&VTout[(((size_t)(bb * 16 + (hd >> 6)) * 64) + (hd & 63)) * 2048 + ss] = o;
      } else {
#pragma unroll
        for (int r = 0; r < 4; ++r) {
          int row = row0 + wm * (BM / 2) + mt * 16 + lg * 4 + r;
          float v = acc[mt][nt][r] + bv;
          if constexpr (sizeof(OutT) == 2)
            C[(size_t)row * N + col] = f2bf(v);
          else
            C[(size_t)row * N + col] = v;
        }
      }
    }
  }
}

// ---------- flash attention ----------
// 512 blocks (XCD-swizzled) x 512 threads (8 waves). Block covers 128 q-rows
// of one (b,h); each wave owns 16 q-rows. KVBLK=64; K,V staged in LDS
// (double-buffered, XOR-swizzled via pre-swizzled global source). Swapped
// QK^T: mfma(K,Q) so a q-row's scores sit in a 16-lane column group.
// Softmax in exp2 domain: Q pre-scaled by (1/sqrt(dh))*log2(e).
__global__ __launch_bounds__(512) void k_attn(const unsigned short* __restrict__ qkv,
                                              const unsigned short* __restrict__ VT,
                                              unsigned short* __restrict__ O) {
  __shared__ unsigned short Ks[2][64 * 64];
  __shared__ unsigned short Vs[2][64 * 64];
  __shared__ unsigned short Ps[8][16 * 64];

  const int bid = blockIdx.x;             // 0..511
  const int xcd = bid & 7, idx = bid >> 3;
  const int bh = xcd + (idx >> 4) * 8;    // 16 consecutive bids share one (b,h) on one XCD
  const int qblk = idx & 15;
  const int b = bh >> 4, h = bh & 15;
  const int t = threadIdx.x, wave = t >> 6, lane = t & 63;
  const int ln15 = lane & 15, lg = lane >> 4;
  const unsigned short* Qb = qkv + (size_t)b * S_ * 3072 + h * 64;
  const unsigned short* Kb = Qb + 1024;
  const unsigned short* Vb = VT + (size_t)bh * 64 * 2048;  // [dh][s]
  const int q0 = qblk * 128 + wave * 16;

  // Q fragments, pre-scaled by (1/sqrt(dh)) * log2(e) for exp2-domain softmax
  const float qsc = 0.125f * 1.4426950408889634f;
  bf16x8 qf[2];
#pragma unroll
  for (int ks = 0; ks < 2; ++ks) {
    bf16x8 raw = *(const bf16x8*)&Qb[(size_t)(q0 + ln15) * 3072 + ks * 32 + lg * 8];
#pragma unroll
    for (int j = 0; j < 8; ++j)
      qf[ks][j] = (short)f2bf(bf2f((unsigned short)raw[j]) * qsc);
  }

  // hoisted staging addresses (row = t>>3, swizzled col = (t&7)^(row&7))
  const int srow = t >> 3;
  const int scol = (t & 7) ^ (srow & 7);
  const unsigned short* kPtr0 = Kb + (size_t)srow * 3072 + scol * 8;
  const unsigned short* vPtr0 = Vb + (size_t)srow * 2048 + scol * 8;
  char* ldsK0 = (char*)&Ks[0][0] + t * 16;
  char* ldsV0 = (char*)&Vs[0][0] + t * 16;

  auto stage = [&](int bi, int kv) {
    GLL(kPtr0 + (size_t)kv * 3072, ldsK0 + bi * 8192);
    GLL(vPtr0 + kv, ldsV0 + bi * 8192);
  };

  f32x4 acc[4];
#pragma unroll
  for (int dt = 0; dt < 4; ++dt)
    acc[dt] = (f32x4){0.f, 0.f, 0.f, 0.f};
  float m0 = -1e30f, l0 = 0.f;
  unsigned short* Pw = Ps[wave];

  stage(0, 0);
  __syncthreads();
  int buf = 0;

  for (int kv = 0; kv < S_; kv += 64) {
    if (kv + 64 < S_) stage(buf ^ 1, kv + 64);

    // ---- QK^T (swapped): st[kg], q = ln15, key = kg*16+lg*4+r
    f32x4 st[4];
#pragma unroll
    for (int kg = 0; kg < 4; ++kg)
      st[kg] = (f32x4){0.f, 0.f, 0.f, 0.f};
    __builtin_amdgcn_s_setprio(1);
#pragma unroll
    for (int kg = 0; kg < 4; ++kg) {
      int krow = kg * 16 + ln15;
      bf16x8 kf0 = *(const bf16x8*)((const char*)&Ks[buf][0] + swz(krow, lg * 16));
      bf16x8 kf1 = *(const bf16x8*)((const char*)&Ks[buf][0] + swz(krow, 64 + lg * 16));
      st[kg] = __builtin_amdgcn_mfma_f32_16x16x32_bf16(kf0, qf[0], st[kg], 0, 0, 0);
      st[kg] = __builtin_amdgcn_mfma_f32_16x16x32_bf16(kf1, qf[1], st[kg], 0, 0, 0);
    }
    __builtin_amdgcn_s_setprio(0);

    // ---- row max (16 own values, then reduce over lg via shfl 16/32)
    float tm = -1e30f;
#pragma unroll
    for (int kg = 0; kg < 4; ++kg)
      tm = fmaxf(tm, fmaxf(fmaxf(st[kg][0], st[kg][1]),
                           fmaxf(st[kg][2], st[kg][3])));
    tm = fmaxf(tm, __shfl_xor(tm, 16));
    tm = fmaxf(tm, __shfl_xor(tm, 32));

    // ---- defer-max (log2 domain): rescale only when max grew by >11
    if (__any(tm > m0 + 11.0f)) {
      float n0 = fmaxf(m0, tm);
      float r0 = fexp2(m0 - n0);
      m0 = n0; l0 *= r0;
#pragma unroll
      for (int dt = 0; dt < 4; ++dt)
#pragma unroll
        for (int r = 0; r < 4; ++r)
          acc[dt][r] *= r0;
    }

    // ---- P = exp2(st - m), pack to bf16, store to per-wave swizzled LDS tile
    asm volatile("" ::: "memory");
    float ts = 0.f;
#pragma unroll
    for (int kg = 0; kg < 4; ++kg) {
      float p0 = fexp2(st[kg][0] - m0);
      float p1 = fexp2(st[kg][1] - m0);
      float p2 = fexp2(st[kg][2] - m0);
      float p3 = fexp2(st[kg][3] - m0);
      ts += (p0 + p1) + (p2 + p3);
      unsigned int w0, w1;
      asm("v_cvt_pk_bf16_f32 %0, %1, %2" : "=v"(w0) : "v"(p0), "v"(p1));
      asm("v_cvt_pk_bf16_f32 %0, %1, %2" : "=v"(w1) : "v"(p2), "v"(p3));
      *(uint2*)((char*)Pw + swz(ln15, kg * 32 + lg * 8)) = make_uint2(w0, w1);
    }
    ts += __shfl_xor(ts, 16);
    ts += __shfl_xor(ts, 32);
    l0 += ts;
    asm volatile("" ::: "memory");

    // ---- PV: acc[dt] += V^T-frag x P^T-frag over two 32-key chunks
    __builtin_amdgcn_s_setprio(1);
#pragma unroll
    for (int kc = 0; kc < 2; ++kc) {
      bf16x8 pf = *(const bf16x8*)((const char*)Pw + swz(ln15, kc * 64 + lg * 16));
#pragma unroll
      for (int dt = 0; dt < 4; ++dt) {
        bf16x8 vf = *(const bf16x8*)((const char*)&Vs[buf][0] + swz(dt * 16 + ln15, kc * 64 + lg * 16));
        acc[dt] = __builtin_amdgcn_mfma_f32_16x16x32_bf16(vf, pf, acc[dt], 0, 0, 0);
      }
    }
    __builtin_amdgcn_s_setprio(0);
    __syncthreads();
    buf ^= 1;
  }

  // ---- epilogue: out = acc / l, layout D[dh][q] -> O[b, q, h*64+dh]
  float inv = 1.f / l0;
  size_t qglob = q0 + ln15;
  size_t base = ((size_t)b * S_ + qglob) * D_ + h * 64 + lg * 4;
#pragma unroll
  for (int dt = 0; dt < 4; ++dt) {
    ushort4 o;
    o.x = f2bf(acc[dt][0] * inv);
    o.y = f2bf(acc[dt][1] * inv);
    o.z = f2bf(acc[dt][2] * inv);
    o.w = f2bf(acc[dt][3] * inv);
    *(ushort4*)&O[base + (size_t)dt * 16] = o;
  }
}

extern "C" void kernel_launch(void* const* d_in, const int* in_sizes, int n_in,
                              void* d_out, int out_size, void* d_ws, size_t ws_size,
                              hipStream_t stream) {
  const float* x     = (const float*)d_in[0];
  const float* w_qkv = (const float*)d_in[1];
  const float* b_qkv = (const float*)d_in[2];
  const float* w_out = (const float*)d_in[3];
  const float* b_out = (const float*)d_in[4];
  float* out = (float*)d_out;

  char* ws = (char*)d_ws;
  const size_t MiB = (size_t)1 << 20;
  unsigned short* xb   = (unsigned short*)(ws + 0 * MiB);   // 8 MiB  [4096][1024] bf16
  unsigned short* wqT  = (unsigned short*)(ws + 8 * MiB);   // 6 MiB  [3072][1024] bf16
  unsigned short* woT  = (unsigned short*)(ws + 14 * MiB);  // 2 MiB  [1024][1024] bf16
  unsigned short* qkvb = (unsigned short*)(ws + 16 * MiB);  // 24 MiB [4096][3072] bf16 (V third unused)
  unsigned short* VTb  = (unsigned short*)(ws + 40 * MiB);  // 8 MiB  [B*H][64][2048] bf16
  unsigned short* Ab   = (unsigned short*)(ws + 48 * MiB);  // 8 MiB  [4096][1024] bf16

  k_prep<<<8192, 256, 0, stream>>>(x, xb, w_qkv, wqT, w_out, woT);
  k_gemm<128, 128, unsigned short><<<dim3(32, 24), 256, 0, stream>>>(xb, wqT, b_qkv, qkvb, VTb, 4096, 3072, 1024);
  k_attn<<<512, 512, 0, stream>>>(qkvb, VTb, Ab);
  k_gemm<128, 64, float><<<dim3(32, 16), 256, 0, stream>>>(Ab, woT, b_out, out, nullptr, 4096, 1024, 1024);
}

// Round 9
// 200.909 us; speedup vs baseline: 1.1232x; 1.0806x over previous
//
#include <hip/hip_runtime.h>
#include <cstdint>

#define B_ 2
#define S_ 2048
#define D_ 1024
#define H_ 16
#define DH_ 64

typedef short bf16x8 __attribute__((ext_vector_type(8)));
typedef float f32x4 __attribute__((ext_vector_type(4)));

__device__ inline unsigned short f2bf(float f) {
  unsigned int u = __float_as_uint(f);
  u += 0x7fffu + ((u >> 16) & 1u);
  return (unsigned short)(u >> 16);
}

__device__ inline float bf2f(unsigned short h) {
  return __uint_as_float(((unsigned int)h) << 16);
}

// fast 2^x via v_exp_f32
__device__ inline float fexp2(float x) { return __builtin_amdgcn_exp2f(x); }

// XOR-swizzle within a 128B row: spreads the 16B column slots across banks.
__device__ inline int swz(int row, int bytecol) {
  return row * 128 + (bytecol ^ ((row & 7) << 4));
}

#define GLL(gp, lp)                                                            \
  __builtin_amdgcn_global_load_lds(                                            \
      (const __attribute__((address_space(1))) unsigned int*)(gp),             \
      (__attribute__((address_space(3))) unsigned int*)(lp), 16, 0, 0)

// ---------- fused prep: cast x, transpose-cast w_qkv and w_out ----------
__global__ __launch_bounds__(256) void k_prep(const float* __restrict__ x,
                                              unsigned short* __restrict__ xb,
                                              const float* __restrict__ w_qkv,
                                              unsigned short* __restrict__ wqT,
                                              const float* __restrict__ w_out,
                                              unsigned short* __restrict__ woT) {
  __shared__ float tile[32][33];
  const int bid = blockIdx.x;
  const int t = threadIdx.x;
  if (bid < 4096) {
    int i = bid * 256 + t;
    float4 v = reinterpret_cast<const float4*>(x)[i];
    ushort4 o;
    o.x = f2bf(v.x); o.y = f2bf(v.y); o.z = f2bf(v.z); o.w = f2bf(v.w);
    reinterpret_cast<ushort4*>(xb)[i] = o;
    return;
  }
  const float* in;
  unsigned short* out;
  int R, C, bx, by;
  if (bid < 7168) {
    int id = bid - 4096;
    bx = id % 96; by = id / 96;
    in = w_qkv; out = wqT; R = 1024; C = 3072;
  } else {
    int id = bid - 7168;
    bx = id & 31; by = id >> 5;
    in = w_out; out = woT; R = 1024; C = 1024;
  }
  int ct = bx * 32, rt = by * 32;
  int tx = t & 31, ty = t >> 5;
#pragma unroll
  for (int i = 0; i < 32; i += 8)
    tile[ty + i][tx] = in[(size_t)(rt + ty + i) * C + ct + tx];
  __syncthreads();
#pragma unroll
  for (int i = 0; i < 32; i += 8)
    out[(size_t)(ct + ty + i) * R + rt + tx] = f2bf(tile[tx][ty + i]);
}

// ---------- 8-phase 256x256 bf16 GEMM (T2+T3+T4+T5) ----------
// 512 threads, 8 waves 1x8 over M (wave owns rows w*32..+32, all 256 cols).
// BK=64; per K-tile 4 phases, phase p computes cols p*64..+64 (16 MFMA).
// Staging: one half-tile (2 GLL) per phase into buf^1 (order A0,A1,B0,B1).
// Counted vmcnt: vmcnt(4)@p1 (clears B1 of current tile for p2/p3 reads),
// vmcnt(2)@p3 (clears A0,A1,B0 of next tile for its p0/p1 reads).
// Raw s_barrier (NOT __syncthreads) so vmcnt stays counted.
#define READB(p)                                                               \
  _Pragma("unroll") for (int nt = 0; nt < 4; ++nt)                             \
  _Pragma("unroll") for (int ks = 0; ks < 2; ++ks)                             \
      bf[nt][ks] = *(const bf16x8*)((const char*)&Bs[cur][0] +                 \
                   swz((p) * 64 + nt * 16 + ln15, ks * 64 + lg * 16));

#define STAGEPIECE(h)                                                          \
  _Pragma("unroll") for (int j = 0; j < 2; ++j) {                              \
    const int rr = ((h) & 1) * 128 + srow + 64 * j;                            \
    const int gc = scol8 ^ (rr & 7);                                           \
    const unsigned short* gsrc =                                               \
        (((h) < 2) ? (A + (size_t)(row0 + rr) * K)                             \
                   : (BT + (size_t)(col0 + rr) * K)) + k0n + gc * 8;           \
    char* ldst = (char*)(((h) < 2) ? &As[cur ^ 1][0] : &Bs[cur ^ 1][0]) +      \
                 rr * 128 + scol8 * 16;                                        \
    GLL(gsrc, ldst);                                                           \
  }

#define MFMAQ(p)                                                               \
  _Pragma("unroll") for (int mt = 0; mt < 2; ++mt)                             \
  _Pragma("unroll") for (int nt = 0; nt < 4; ++nt) {                           \
    acc[mt][(p) * 4 + nt] = __builtin_amdgcn_mfma_f32_16x16x32_bf16(           \
        af[mt][0], bf[nt][0], acc[mt][(p) * 4 + nt], 0, 0, 0);                 \
    acc[mt][(p) * 4 + nt] = __builtin_amdgcn_mfma_f32_16x16x32_bf16(           \
        af[mt][1], bf[nt][1], acc[mt][(p) * 4 + nt], 0, 0, 0);                 \
  }

template <typename OutT>
__global__ __launch_bounds__(512, 2) void k_gemm8(const unsigned short* __restrict__ A,
                                                  const unsigned short* __restrict__ BT,
                                                  const float* __restrict__ bias,
                                                  OutT* __restrict__ C,
                                                  unsigned short* __restrict__ VTout,
                                                  int M, int N, int K) {
  __shared__ unsigned short As[2][256 * 64];
  __shared__ unsigned short Bs[2][256 * 64];
  const int t = threadIdx.x;
  const int lane = t & 63;
  const int w = t >> 6;                 // wave 0..7 -> rows w*32..+32
  const int ln15 = lane & 15, lg = lane >> 4;
  const int srow = t >> 3;              // 0..63
  const int scol8 = t & 7;
  const int nwg = gridDim.x * gridDim.y;
  const int flat = blockIdx.y * gridDim.x + blockIdx.x;
  const int cpx = nwg >> 3;
  const int sid = (flat & 7) * cpx + (flat >> 3);
  const int row0 = (sid % gridDim.x) * 256, col0 = (sid / gridDim.x) * 256;

  f32x4 acc[2][16];
#pragma unroll
  for (int i = 0; i < 2; ++i)
#pragma unroll
    for (int j = 0; j < 16; ++j)
      acc[i][j] = (f32x4){0.f, 0.f, 0.f, 0.f};

  const int NTILES = K / 64;
  // prologue: stage tile 0 fully into buf 0
  {
    const int k0n = 0;
    const int cur = 1;  // stage target = cur^1 = 0
    STAGEPIECE(0); STAGEPIECE(1); STAGEPIECE(2); STAGEPIECE(3);
  }
  asm volatile("s_waitcnt vmcnt(0)" ::: "memory");
  __builtin_amdgcn_s_barrier();

  int cur = 0;
  for (int kt = 0; kt < NTILES; ++kt) {
    const int k0n = (kt + 1) * 64;
    const bool more = (kt + 1) < NTILES;
    bf16x8 af[2][2];
    // ---- phase 0: read A frags + B cols 0-63, stage A0'
    {
      bf16x8 bf[4][2];
      READB(0);
#pragma unroll
      for (int mt = 0; mt < 2; ++mt)
#pragma unroll
        for (int ks = 0; ks < 2; ++ks)
          af[mt][ks] = *(const bf16x8*)((const char*)&As[cur][0] +
                       swz(w * 32 + mt * 16 + ln15, ks * 64 + lg * 16));
      if (more) { STAGEPIECE(0); }
      __builtin_amdgcn_s_barrier();
      __builtin_amdgcn_s_setprio(1);
      MFMAQ(0);
      __builtin_amdgcn_s_setprio(0);
      __builtin_amdgcn_s_barrier();
    }
    // ---- phase 1: B cols 64-127, stage A1', vmcnt clears current B1
    {
      bf16x8 bf[4][2];
      READB(1);
      if (more) {
        STAGEPIECE(1);
        asm volatile("s_waitcnt vmcnt(4)" ::: "memory");
      } else {
        asm volatile("s_waitcnt vmcnt(0)" ::: "memory");
      }
      __builtin_amdgcn_s_barrier();
      __builtin_amdgcn_s_setprio(1);
      MFMAQ(1);
      __builtin_amdgcn_s_setprio(0);
      __builtin_amdgcn_s_barrier();
    }
    // ---- phase 2: B cols 128-191, stage B0'
    {
      bf16x8 bf[4][2];
      READB(2);
      if (more) { STAGEPIECE(2); }
      __builtin_amdgcn_s_barrier();
      __builtin_amdgcn_s_setprio(1);
      MFMAQ(2);
      __builtin_amdgcn_s_setprio(0);
      __builtin_amdgcn_s_barrier();
    }
    // ---- phase 3: B cols 192-255, stage B1', vmcnt clears next A0,A1,B0
    {
      bf16x8 bf[4][2];
      READB(3);
      if (more) {
        STAGEPIECE(3);
        asm volatile("s_waitcnt vmcnt(2)" ::: "memory");
      }
      __builtin_amdgcn_s_barrier();
      __builtin_amdgcn_s_setprio(1);
      MFMAQ(3);
      __builtin_amdgcn_s_setprio(0);
      __builtin_amdgcn_s_barrier();
    }
    cur ^= 1;
  }

  // ---- epilogue
#pragma unroll
  for (int mt = 0; mt < 2; ++mt) {
#pragma unroll
    for (int nt = 0; nt < 16; ++nt) {
      int col = col0 + nt * 16 + ln15;
      float bv = bias[col];
      if (VTout != nullptr && col >= 2048) {
        int hd = col - 2048;
        int row = row0 + w * 32 + mt * 16 + lg * 4;
        int bb = row >> 11, ss = row & 2047;
        ushort4 o;
        o.x = f2bf(acc[mt][nt][0] + bv);
        o.y = f2bf(acc[mt][nt][1] + bv);
        o.z = f2bf(acc[mt][nt][2] + bv);
        o.w = f2bf(acc[mt][nt][3] + bv);
        *(ushort4*)&VTout[(((size_t)(bb * 16 + (hd >> 6)) * 64) + (hd & 63)) * 2048 + ss] = o;
      } else {
#pragma unroll
        for (int r = 0; r < 4; ++r) {
          int row = row0 + w * 32 + mt * 16 + lg * 4 + r;
          float v = acc[mt][nt][r] + bv;
          if constexpr (sizeof(OutT) == 2)
            C[(size_t)row * N + col] = f2bf(v);
          else
            C[(size_t)row * N + col] = v;
        }
      }
    }
  }
}

// ---------- m97-style GEMM (used for the small out-proj) ----------
template <int BM, int BN, typename OutT>
__global__ __launch_bounds__(256) void k_gemm(const unsigned short* __restrict__ A,
                                              const unsigned short* __restrict__ BT,
                                              const float* __restrict__ bias,
                                              OutT* __restrict__ C,
                                              unsigned short* __restrict__ VTout,
                                              int M, int N, int K) {
  constexpr int MT = BM / 32, NT = BN / 32;
  __shared__ unsigned short As2[BM * 64];
  __shared__ unsigned short Bs2[BN * 64];
  const int t = threadIdx.x;
  const int lane = t & 63;
  const int wave = t >> 6;
  const int wm = wave >> 1, wn = wave & 1;
  const int ln15 = lane & 15, lg = lane >> 4;
  const int nwg = gridDim.x * gridDim.y;
  const int flat = blockIdx.y * gridDim.x + blockIdx.x;
  const int cpx = nwg >> 3;
  const int sid = (flat & 7) * cpx + (flat >> 3);
  const int row0 = (sid % gridDim.x) * BM, col0 = (sid / gridDim.x) * BN;
  f32x4 acc[MT][NT];
#pragma unroll
  for (int i = 0; i < MT; ++i)
#pragma unroll
    for (int j = 0; j < NT; ++j)
      acc[i][j] = (f32x4){0.f, 0.f, 0.f, 0.f};

  for (int k0 = 0; k0 < K; k0 += 64) {
    __syncthreads();
#pragma unroll
    for (int i = 0; i < BM / 32; ++i) {
      int chunk = i * 256 + t;
      int r = chunk >> 3;
      int cb = (chunk & 7) * 16;
      GLL((const char*)(A + (size_t)(row0 + r) * K + k0) + cb, (char*)As2 + chunk * 16);
    }
#pragma unroll
    for (int i = 0; i < BN / 32; ++i) {
      int chunk = i * 256 + t;
      int r = chunk >> 3;
      int cb = (chunk & 7) * 16;
      GLL((const char*)(BT + (size_t)(col0 + r) * K + k0) + cb, (char*)Bs2 + chunk * 16);
    }
    __syncthreads();
#pragma unroll
    for (int ks = 0; ks < 2; ++ks) {
      bf16x8 af[MT], bf[NT];
#pragma unroll
      for (int mt = 0; mt < MT; ++mt)
        af[mt] = *(const bf16x8*)&As2[(wm * (BM / 2) + mt * 16 + ln15) * 64 + ks * 32 + lg * 8];
#pragma unroll
      for (int nt = 0; nt < NT; ++nt)
        bf[nt] = *(const bf16x8*)&Bs2[(wn * (BN / 2) + nt * 16 + ln15) * 64 + ks * 32 + lg * 8];
#pragma unroll
      for (int mt = 0; mt < MT; ++mt)
#pragma unroll
        for (int nt = 0; nt < NT; ++nt)
          acc[mt][nt] = __builtin_amdgcn_mfma_f32_16x16x32_bf16(af[mt], bf[nt], acc[mt][nt], 0, 0, 0);
    }
  }
#pragma unroll
  for (int mt = 0; mt < MT; ++mt) {
#pragma unroll
    for (int nt = 0; nt < NT; ++nt) {
      int col = col0 + wn * (BN / 2) + nt * 16 + ln15;
      float bv = bias[col];
#pragma unroll
      for (int r = 0; r < 4; ++r) {
        int row = row0 + wm * (BM / 2) + mt * 16 + lg * 4 + r;
        float v = acc[mt][nt][r] + bv;
        if constexpr (sizeof(OutT) == 2)
          C[(size_t)row * N + col] = f2bf(v);
        else
          C[(size_t)row * N + col] = v;
      }
    }
  }
}

// ---------- flash attention (R6 shape: 8 waves x 16 q-rows) ----------
__global__ __launch_bounds__(512) void k_attn(const unsigned short* __restrict__ qkv,
                                              const unsigned short* __restrict__ VT,
                                              unsigned short* __restrict__ O) {
  __shared__ unsigned short Ks[2][64 * 64];
  __shared__ unsigned short Vs[2][64 * 64];
  __shared__ unsigned short Ps[8][16 * 64];

  const int bid = blockIdx.x;
  const int xcd = bid & 7, idx = bid >> 3;
  const int bh = xcd + (idx >> 4) * 8;
  const int qblk = idx & 15;
  const int b = bh >> 4, h = bh & 15;
  const int t = threadIdx.x, wave = t >> 6, lane = t & 63;
  const int ln15 = lane & 15, lg = lane >> 4;
  const unsigned short* Qb = qkv + (size_t)b * S_ * 3072 + h * 64;
  const unsigned short* Kb = Qb + 1024;
  const unsigned short* Vb = VT + (size_t)bh * 64 * 2048;
  const int q0 = qblk * 128 + wave * 16;

  const float qsc = 0.125f * 1.4426950408889634f;
  bf16x8 qf[2];
#pragma unroll
  for (int ks = 0; ks < 2; ++ks) {
    bf16x8 raw = *(const bf16x8*)&Qb[(size_t)(q0 + ln15) * 3072 + ks * 32 + lg * 8];
#pragma unroll
    for (int j = 0; j < 8; ++j)
      qf[ks][j] = (short)f2bf(bf2f((unsigned short)raw[j]) * qsc);
  }

  const int srow = t >> 3;
  const int scol = (t & 7) ^ (srow & 7);
  const unsigned short* kPtr0 = Kb + (size_t)srow * 3072 + scol * 8;
  const unsigned short* vPtr0 = Vb + (size_t)srow * 2048 + scol * 8;
  char* ldsK0 = (char*)&Ks[0][0] + t * 16;
  char* ldsV0 = (char*)&Vs[0][0] + t * 16;

  auto stage = [&](int bi, int kv) {
    GLL(kPtr0 + (size_t)kv * 3072, ldsK0 + bi * 8192);
    GLL(vPtr0 + kv, ldsV0 + bi * 8192);
  };

  f32x4 acc[4];
#pragma unroll
  for (int dt = 0; dt < 4; ++dt)
    acc[dt] = (f32x4){0.f, 0.f, 0.f, 0.f};
  float m0 = -1e30f, l0 = 0.f;
  unsigned short* Pw = Ps[wave];

  stage(0, 0);
  __syncthreads();
  int buf = 0;

  for (int kv = 0; kv < S_; kv += 64) {
    if (kv + 64 < S_) stage(buf ^ 1, kv + 64);

    f32x4 st[4];
#pragma unroll
    for (int kg = 0; kg < 4; ++kg)
      st[kg] = (f32x4){0.f, 0.f, 0.f, 0.f};
    __builtin_amdgcn_s_setprio(1);
#pragma unroll
    for (int kg = 0; kg < 4; ++kg) {
      int krow = kg * 16 + ln15;
      bf16x8 kf0 = *(const bf16x8*)((const char*)&Ks[buf][0] + swz(krow, lg * 16));
      bf16x8 kf1 = *(const bf16x8*)((const char*)&Ks[buf][0] + swz(krow, 64 + lg * 16));
      st[kg] = __builtin_amdgcn_mfma_f32_16x16x32_bf16(kf0, qf[0], st[kg], 0, 0, 0);
      st[kg] = __builtin_amdgcn_mfma_f32_16x16x32_bf16(kf1, qf[1], st[kg], 0, 0, 0);
    }
    __builtin_amdgcn_s_setprio(0);

    float tm = -1e30f;
#pragma unroll
    for (int kg = 0; kg < 4; ++kg)
      tm = fmaxf(tm, fmaxf(fmaxf(st[kg][0], st[kg][1]),
                           fmaxf(st[kg][2], st[kg][3])));
    tm = fmaxf(tm, __shfl_xor(tm, 16));
    tm = fmaxf(tm, __shfl_xor(tm, 32));

    if (__any(tm > m0 + 11.0f)) {
      float n0 = fmaxf(m0, tm);
      float r0 = fexp2(m0 - n0);
      m0 = n0; l0 *= r0;
#pragma unroll
      for (int dt = 0; dt < 4; ++dt)
#pragma unroll
        for (int r = 0; r < 4; ++r)
          acc[dt][r] *= r0;
    }

    asm volatile("" ::: "memory");
    float ts = 0.f;
#pragma unroll
    for (int kg = 0; kg < 4; ++kg) {
      float p0 = fexp2(st[kg][0] - m0);
      float p1 = fexp2(st[kg][1] - m0);
      float p2 = fexp2(st[kg][2] - m0);
      float p3 = fexp2(st[kg][3] - m0);
      ts += (p0 + p1) + (p2 + p3);
      unsigned int w0, w1;
      asm("v_cvt_pk_bf16_f32 %0, %1, %2" : "=v"(w0) : "v"(p0), "v"(p1));
      asm("v_cvt_pk_bf16_f32 %0, %1, %2" : "=v"(w1) : "v"(p2), "v"(p3));
      *(uint2*)((char*)Pw + swz(ln15, kg * 32 + lg * 8)) = make_uint2(w0, w1);
    }
    ts += __shfl_xor(ts, 16);
    ts += __shfl_xor(ts, 32);
    l0 += ts;
    asm volatile("" ::: "memory");

    __builtin_amdgcn_s_setprio(1);
#pragma unroll
    for (int kc = 0; kc < 2; ++kc) {
      bf16x8 pf = *(const bf16x8*)((const char*)Pw + swz(ln15, kc * 64 + lg * 16));
#pragma unroll
      for (int dt = 0; dt < 4; ++dt) {
        bf16x8 vf = *(const bf16x8*)((const char*)&Vs[buf][0] + swz(dt * 16 + ln15, kc * 64 + lg * 16));
        acc[dt] = __builtin_amdgcn_mfma_f32_16x16x32_bf16(vf, pf, acc[dt], 0, 0, 0);
      }
    }
    __builtin_amdgcn_s_setprio(0);
    __syncthreads();
    buf ^= 1;
  }

  float inv = 1.f / l0;
  size_t qglob = q0 + ln15;
  size_t base = ((size_t)b * S_ + qglob) * D_ + h * 64 + lg * 4;
#pragma unroll
  for (int dt = 0; dt < 4; ++dt) {
    ushort4 o;
    o.x = f2bf(acc[dt][0] * inv);
    o.y = f2bf(acc[dt][1] * inv);
    o.z = f2bf(acc[dt][2] * inv);
    o.w = f2bf(acc[dt][3] * inv);
    *(ushort4*)&O[base + (size_t)dt * 16] = o;
  }
}

extern "C" void kernel_launch(void* const* d_in, const int* in_sizes, int n_in,
                              void* d_out, int out_size, void* d_ws, size_t ws_size,
                              hipStream_t stream) {
  const float* x     = (const float*)d_in[0];
  const float* w_qkv = (const float*)d_in[1];
  const float* b_qkv = (const float*)d_in[2];
  const float* w_out = (const float*)d_in[3];
  const float* b_out = (const float*)d_in[4];
  float* out = (float*)d_out;

  char* ws = (char*)d_ws;
  const size_t MiB = (size_t)1 << 20;
  unsigned short* xb   = (unsigned short*)(ws + 0 * MiB);
  unsigned short* wqT  = (unsigned short*)(ws + 8 * MiB);
  unsigned short* woT  = (unsigned short*)(ws + 14 * MiB);
  unsigned short* qkvb = (unsigned short*)(ws + 16 * MiB);
  unsigned short* VTb  = (unsigned short*)(ws + 40 * MiB);
  unsigned short* Ab   = (unsigned short*)(ws + 48 * MiB);

  k_prep<<<8192, 256, 0, stream>>>(x, xb, w_qkv, wqT, w_out, woT);
  k_gemm8<unsigned short><<<dim3(16, 12), 512, 0, stream>>>(xb, wqT, b_qkv, qkvb, VTb, 4096, 3072, 1024);
  k_attn<<<512, 512, 0, stream>>>(qkvb, VTb, Ab);
  k_gemm<128, 64, float><<<dim3(32, 16), 256, 0, stream>>>(Ab, woT, b_out, out, nullptr, 4096, 1024, 1024);
}